// Round 2
// baseline (298.478 us; speedup 1.0000x reference)
//
#include <hip/hip_runtime.h>
#include <math.h>

// Problem constants (reference: B,H,Q_TOK,D = 8,12,577,64)
constexpr int BB = 8, HH = 12, QT = 577, DD = 64;
constexpr int NTOK = BB * HH * QT;                        // 55392 tokens
constexpr long long MASK_ELEMS = (long long)NTOK * QT;    // 31,961,184 (divisible by 4)
constexpr long long NVEC = MASK_ELEMS / 4;                // 7,990,296 float4 vectors
constexpr int MASK_BLOCKS = (int)((NVEC + 255) / 256);    // 31213

using f4 = __attribute__((ext_vector_type(4))) float;

// ---------------------------------------------------------------------------
// Kernel A (unchanged, verified): per-token sigma-MLP -> Sigma region.
// One WAVE per token, __shfl broadcast of the query row, no LDS/barriers.
// ---------------------------------------------------------------------------
__global__ __launch_bounds__(256)
void mlp_sigma(const float* __restrict__ query,   // (NTOK, 64)
               const float* __restrict__ W1,      // (64, 64)
               const float* __restrict__ b1,      // (64)
               const float* __restrict__ W2,      // (64, 3)
               const float* __restrict__ b2,      // (3)
               f4* __restrict__ Sig)              // (NTOK) {sy2, cov, cov, sx2}
{
    const int token = (blockIdx.x * 256 + threadIdx.x) >> 6;
    const int lane  = threadIdx.x & 63;
    if (token >= NTOK) return;

    const float qv = query[(size_t)token * DD + lane];
    float acc = b1[lane];
#pragma unroll
    for (int i = 0; i < DD; ++i)
        acc = fmaf(__shfl(qv, i), W1[i * DD + lane], acc);  // readlane broadcast
    const float h = 0.5f * acc * (1.0f + erff(acc * 0.7071067811865476f));

    float p0 = h * W2[lane * 3 + 0];
    float p1 = h * W2[lane * 3 + 1];
    float p2 = h * W2[lane * 3 + 2];
#pragma unroll
    for (int off = 32; off > 0; off >>= 1) {
        p0 += __shfl_xor(p0, off);
        p1 += __shfl_xor(p1, off);
        p2 += __shfl_xor(p2, off);
    }
    if (lane == 0) {
        const float sy  = expf(p0 + b2[0]) + 1.0f;   // precise ocml for Sigma
        const float sx  = expf(p1 + b2[1]) + 1.0f;
        const float rho = tanhf(p2 + b2[2]) * 0.99f;
        const float cov = sy * sx * rho;
        f4 s; s.x = sy * sy; s.y = cov; s.z = cov; s.w = sx * sx;
        Sig[token] = s;
    }
}

// ---------------------------------------------------------------------------
// Kernel B (rewritten): FLAT-indexed mask. Each thread owns 4 consecutive
// elements of the flat (NTOK*577) mask array -> all u loads and mask stores
// are 16B-aligned dwordx4 (1 KB per wave-instruction), the m13-measured BW
// sweet spot. Per element we recompute (token,k,q) via compiler magic-divs
// and read Sigma (L1/L2-resident, near-uniform per wave). Math per element:
//   0.5*quad = (S.w*dy^2 - 2*S.y*dy*dx + S.x*dx^2) / (2*det)
//   E = exp(0.5*quad) = 1/p   (row max of p is exactly 1: dy=dx=0 at k==q
//                              and at CLS row/col -> max-divide is a no-op)
//   mask = sigmoid(logit(p)+logit(u)) = u / (u + (E-1)*(1-u))     [T == 1]
// Edges: hq==0 -> E=1 -> m=u*rcp(u)~=1 (ref 1.0); E=inf -> m=0 (ref 0).
// General T via wave-uniform cold branch (exact same algebra as before).
// ---------------------------------------------------------------------------
__global__ __launch_bounds__(256)
void mask_flat(const float* __restrict__ u,      // (NTOK*577) flat
               const float* __restrict__ temp,   // (1)
               float* __restrict__ out)          // mask then Sigma
{
    const f4* __restrict__ Sig = (const f4*)(out + MASK_ELEMS);
    const long long v = (long long)blockIdx.x * 256 + threadIdx.x;
    if (v >= NVEC) return;
    const unsigned e0 = (unsigned)(v * 4);

    const float invT = 1.0f / temp[0];
    const f4 uv4 = *(const f4*)(u + e0);          // aligned dwordx4
    f4 m4;

#pragma unroll
    for (int c = 0; c < 4; ++c) {
        const unsigned e     = e0 + (unsigned)c;
        const unsigned token = e / 577u;          // magic-mul
        const unsigned k     = e - token * 577u;
        const unsigned q     = token - (token / 577u) * 577u;

        // geometry: idx(i) = ((i-1)/24, (i-1)%24), CLS row/col zero-padded
        const int qm1 = (q > 0u) ? (int)q - 1 : 0;
        const int km1 = (k > 0u) ? (int)k - 1 : 0;
        const int qr = qm1 / 24, qcc = qm1 - qr * 24;
        const int kr = km1 / 24, kcc = km1 - kr * 24;
        float dy = (float)(qr - kr);
        float dx = (float)(qcc - kcc);
        if ((q == 0u) | (k == 0u)) { dy = 0.0f; dx = 0.0f; }

        const f4 S = Sig[token];                  // ~886 KB total, cache-hit
        const float det2 = 2.0f * fmaf(S.x, S.w, -S.y * S.y);   // 2*det > 0
        const float qraw = fmaf(S.w, dy * dy,
                           fmaf(-2.0f * S.y, dy * dx, S.x * (dx * dx)));
        const float hq = fmaxf(qraw * __fdividef(1.0f, det2), 0.0f);
        const float E  = __expf(hq);              // hq==0 -> exactly 1
        const float a  = E - 1.0f;
        const float uv = uv4[c];
        float m = __fdividef(uv, fmaf(a, 1.0f - uv, uv));
        if (invT != 1.0f) {                       // uniform cold path (T != 1)
            const float rr = __fdividef(a * (1.0f - uv), uv);
            m = __fdividef(1.0f, 1.0f + __expf(__logf(rr) * invT));
        }
        m4[c] = m;
    }
    __builtin_nontemporal_store(m4, (f4*)(out + e0));   // aligned dwordx4
}

extern "C" void kernel_launch(void* const* d_in, const int* in_sizes, int n_in,
                              void* d_out, int out_size, void* d_ws, size_t ws_size,
                              hipStream_t stream) {
    const float* query = (const float*)d_in[0];
    const float* W1    = (const float*)d_in[1];
    const float* b1    = (const float*)d_in[2];
    const float* W2    = (const float*)d_in[3];
    const float* b2    = (const float*)d_in[4];
    // d_in[5] = dists: closed form inside mask_flat
    const float* u     = (const float*)d_in[6];
    const float* temp  = (const float*)d_in[7];
    float* out = (float*)d_out;

    f4* Sig = (f4*)(out + MASK_ELEMS);
    mlp_sigma<<<dim3(NTOK / 4), dim3(256), 0, stream>>>(query, W1, b1, W2, b2, Sig);
    mask_flat<<<dim3(MASK_BLOCKS), dim3(256), 0, stream>>>(u, temp, out);
}